// Round 1
// baseline (85.470 us; speedup 1.0000x reference)
//
#include <hip/hip_runtime.h>
#include <math.h>

#define EMBED 1280
#define NHEAD 20
#define HDIM 64
#define LENC 8192
#define CHUNK 512
#define NCHUNK (LENC / CHUNK)   // 16
#define QSCALE 0.125f           // 64^-0.5

// ---------------------------------------------------------------------------
// Generic 1280x1280 matvec: y[j] = scale * (sum_i W[j][i]*x[i] + b[j])
// One wave per output row, float4 loads. grid = 1280/4 rows-per-block blocks.
// ---------------------------------------------------------------------------
__global__ __launch_bounds__(256) void matvec1280(
    const float* __restrict__ W, const float* __restrict__ x,
    const float* __restrict__ b, float* __restrict__ y, float scale) {
  int j = blockIdx.x * 4 + (threadIdx.x >> 6);  // output row
  int lane = threadIdx.x & 63;
  const float4* Wr = reinterpret_cast<const float4*>(W + (size_t)j * EMBED);
  const float4* x4 = reinterpret_cast<const float4*>(x);
  float acc = 0.f;
#pragma unroll
  for (int k = 0; k < 5; ++k) {  // 1280/4 = 320 float4 = 5 * 64 lanes
    float4 wv = Wr[lane + 64 * k];
    float4 xv = x4[lane + 64 * k];
    acc += wv.x * xv.x + wv.y * xv.y + wv.z * xv.z + wv.w * xv.w;
  }
#pragma unroll
  for (int m = 32; m > 0; m >>= 1) acc += __shfl_xor(acc, m);
  if (lane == 0) y[j] = scale * (acc + b[j]);
}

// ---------------------------------------------------------------------------
// Flash-decode partial: one block per (head, chunk of 512 keys).
// Computes local max M, local sum S = sum exp(score-M), and partial
// o[d] = sum_l exp(score_l - M) * V[l][d].  Stored as [M, S, o[64]] (66 f).
// ---------------------------------------------------------------------------
__global__ __launch_bounds__(256) void attn_partial(
    const float* __restrict__ K, const float* __restrict__ V,
    const float* __restrict__ q, float* __restrict__ part) {
  int blk = blockIdx.x;  // 0..NHEAD*NCHUNK-1
  int h = blk / NCHUNK;
  int c = blk % NCHUNK;
  int tid = threadIdx.x;
  int w = tid >> 6;      // wave 0..3
  int lane = tid & 63;
  int l0 = c * CHUNK;

  __shared__ float sc[CHUNK];
  __shared__ float red[256];
  __shared__ float ovec[4][HDIM];

  float qd = q[h * HDIM + lane];
  const float* Kh = K + (size_t)h * LENC * HDIM;
  const float* Vh = V + (size_t)h * LENC * HDIM;

  // --- scores: each wave handles rows l0 + w + 4*r, coalesced 256B/row ---
#pragma unroll 4
  for (int r = 0; r < CHUNK / 4; ++r) {
    int li = l0 + w + 4 * r;
    float s = Kh[(size_t)li * HDIM + lane] * qd;
#pragma unroll
    for (int m = 32; m > 0; m >>= 1) s += __shfl_xor(s, m);
    if (lane == 0) sc[li - l0] = s;
  }
  __syncthreads();

  // --- block max over 512 scores ---
  float mloc = fmaxf(sc[tid], sc[tid + 256]);
  red[tid] = mloc;
  __syncthreads();
  for (int st = 128; st > 0; st >>= 1) {
    if (tid < st) red[tid] = fmaxf(red[tid], red[tid + st]);
    __syncthreads();
  }
  float M = red[0];
  __syncthreads();

  // --- exp + block sum ---
  float e0 = expf(sc[tid] - M);
  float e1 = expf(sc[tid + 256] - M);
  sc[tid] = e0;
  sc[tid + 256] = e1;
  red[tid] = e0 + e1;
  __syncthreads();
  for (int st = 128; st > 0; st >>= 1) {
    if (tid < st) red[tid] += red[tid + st];
    __syncthreads();
  }
  float S = red[0];
  __syncthreads();

  // --- P @ V partial: lane d accumulates over this wave's rows ---
  float acc = 0.f;
#pragma unroll 4
  for (int r = 0; r < CHUNK / 4; ++r) {
    int li = l0 + w + 4 * r;
    acc += sc[li - l0] * Vh[(size_t)li * HDIM + lane];
  }
  ovec[w][lane] = acc;
  __syncthreads();

  if (w == 0) {
    float o = ovec[0][lane] + ovec[1][lane] + ovec[2][lane] + ovec[3][lane];
    float* p = part + (size_t)(h * NCHUNK + c) * 66;
    if (lane == 0) { p[0] = M; p[1] = S; }
    p[2 + lane] = o;
  }
}

// ---------------------------------------------------------------------------
// Combine partials per head: 20 blocks x 64 threads.
// ---------------------------------------------------------------------------
__global__ __launch_bounds__(64) void attn_combine(
    const float* __restrict__ part, float* __restrict__ attn_out) {
  int h = blockIdx.x;
  int lane = threadIdx.x;
  const float* p = part + (size_t)h * NCHUNK * 66;
  float M = -INFINITY;
#pragma unroll
  for (int c = 0; c < NCHUNK; ++c) M = fmaxf(M, p[c * 66]);
  float S = 0.f, o = 0.f;
#pragma unroll
  for (int c = 0; c < NCHUNK; ++c) {
    float f = expf(p[c * 66] - M);
    S += p[c * 66 + 1] * f;
    o += p[c * 66 + 2 + lane] * f;
  }
  attn_out[h * HDIM + lane] = o / S;
}

// ---------------------------------------------------------------------------

extern "C" void kernel_launch(void* const* d_in, const int* in_sizes, int n_in,
                              void* d_out, int out_size, void* d_ws, size_t ws_size,
                              hipStream_t stream) {
  const float* hs    = (const float*)d_in[0];  // [1280]
  const float* Kc    = (const float*)d_in[1];  // [20,8192,64]
  const float* Vc    = (const float*)d_in[2];  // [20,8192,64]
  const float* q_w   = (const float*)d_in[3];  // [1280,1280]
  const float* q_b   = (const float*)d_in[4];  // [1280]
  const float* out_w = (const float*)d_in[5];  // [1280,1280]
  const float* out_b = (const float*)d_in[6];  // [1280]
  float* out = (float*)d_out;                  // [1280]

  float* ws = (float*)d_ws;
  float* qv       = ws;                // 1280
  float* attn_out = ws + EMBED;        // 1280
  float* part     = ws + 2 * EMBED;    // 20*16*66 = 21120

  // 1. q projection (+ scale)
  matvec1280<<<EMBED / 4, 256, 0, stream>>>(q_w, hs, q_b, qv, QSCALE);
  // 2. flash-decode partials over (head, chunk)
  attn_partial<<<NHEAD * NCHUNK, 256, 0, stream>>>(Kc, Vc, qv, part);
  // 3. combine
  attn_combine<<<NHEAD, 64, 0, stream>>>(part, attn_out);
  // 4. output projection
  matvec1280<<<EMBED / 4, 256, 0, stream>>>(out_w, attn_out, out_b, out, 1.0f);
}

// Round 2
// 34.392 us; speedup vs baseline: 2.4852x; 2.4852x over previous
//
#include <hip/hip_runtime.h>
#include <math.h>

#define EMBED 1280
#define NHEAD 20
#define HDIM 64
#define LENC 8192
#define CHUNK 128
#define NCHUNK (LENC / CHUNK)   // 64
#define PREC 72                 // floats per partial record: [M,S,pad,pad,o[64]]
#define QSCALE 0.125f           // 64^-0.5

// ---------------------------------------------------------------------------
// Generic 1280x1280 matvec: y[j] = scale * (sum_i W[j][i]*x[i] + b[j])
// One wave per output row, float4 loads.
// ---------------------------------------------------------------------------
__global__ __launch_bounds__(256) void matvec1280(
    const float* __restrict__ W, const float* __restrict__ x,
    const float* __restrict__ b, float* __restrict__ y, float scale) {
  int j = blockIdx.x * 4 + (threadIdx.x >> 6);  // output row
  int lane = threadIdx.x & 63;
  const float4* Wr = reinterpret_cast<const float4*>(W + (size_t)j * EMBED);
  const float4* x4 = reinterpret_cast<const float4*>(x);
  float acc = 0.f;
#pragma unroll
  for (int k = 0; k < 5; ++k) {  // 1280/4 = 320 float4 = 5 * 64 lanes
    float4 wv = Wr[lane + 64 * k];
    float4 xv = x4[lane + 64 * k];
    acc += wv.x * xv.x + wv.y * xv.y + wv.z * xv.z + wv.w * xv.w;
  }
#pragma unroll
  for (int m = 32; m > 0; m >>= 1) acc += __shfl_xor(acc, m);
  if (lane == 0) y[j] = scale * (acc + b[j]);
}

// ---------------------------------------------------------------------------
// Flash-decode partial: one block per (head, chunk of 128 keys).
// float4 loads: 16 lanes span one 64-float K/V row -> 4 rows/wave/iter.
// Record: [M, S, pad, pad, o[64]] (72 floats, 16B-aligned o).
// ---------------------------------------------------------------------------
__global__ __launch_bounds__(256) void attn_partial(
    const float* __restrict__ K, const float* __restrict__ V,
    const float* __restrict__ q, float* __restrict__ part) {
  int blk = blockIdx.x;  // 0..NHEAD*NCHUNK-1
  int h = blk / NCHUNK;
  int c = blk % NCHUNK;
  int tid = threadIdx.x;
  int w = tid >> 6;       // wave 0..3
  int lane = tid & 63;
  int grp = lane >> 4;    // row-group 0..3 within wave
  int l16 = lane & 15;    // float4 index within row

  __shared__ float sc[CHUNK];
  __shared__ float red[8];
  __shared__ float4 ovec[4][16];

  const float4* Kh4 = reinterpret_cast<const float4*>(
      K + (size_t)h * LENC * HDIM + (size_t)c * CHUNK * HDIM);
  const float4* Vh4 = reinterpret_cast<const float4*>(
      V + (size_t)h * LENC * HDIM + (size_t)c * CHUNK * HDIM);
  float4 qv = reinterpret_cast<const float4*>(q + h * HDIM)[l16];

  // --- scores: wave w covers rows [w*32, w*32+32), 4 rows per iter ---
#pragma unroll
  for (int it = 0; it < CHUNK / 16; ++it) {   // 8 iters
    int row = w * (CHUNK / 4) + it * 4 + grp;
    float4 kv = Kh4[row * 16 + l16];
    float s = kv.x * qv.x + kv.y * qv.y + kv.z * qv.z + kv.w * qv.w;
    s += __shfl_xor(s, 1);
    s += __shfl_xor(s, 2);
    s += __shfl_xor(s, 4);
    s += __shfl_xor(s, 8);
    if (l16 == 0) sc[row] = s;
  }
  __syncthreads();

  // --- block max over 128 scores ---
  float m = (tid < CHUNK) ? sc[tid] : -INFINITY;
#pragma unroll
  for (int msk = 32; msk > 0; msk >>= 1) m = fmaxf(m, __shfl_xor(m, msk));
  if (lane == 0) red[w] = m;
  __syncthreads();
  float M = fmaxf(fmaxf(red[0], red[1]), fmaxf(red[2], red[3]));

  // --- exp + block sum (each thread touches only sc[tid]) ---
  float e = (tid < CHUNK) ? expf(sc[tid] - M) : 0.f;
  if (tid < CHUNK) sc[tid] = e;
  float ssum = e;
#pragma unroll
  for (int msk = 32; msk > 0; msk >>= 1) ssum += __shfl_xor(ssum, msk);
  if (lane == 0) red[4 + w] = ssum;
  __syncthreads();
  float S = red[4] + red[5] + red[6] + red[7];

  // --- P @ V partial: lane accumulates out dims [l16*4, l16*4+4) ---
  float4 acc = make_float4(0.f, 0.f, 0.f, 0.f);
#pragma unroll
  for (int it = 0; it < CHUNK / 16; ++it) {
    int row = w * (CHUNK / 4) + it * 4 + grp;
    float4 vv = Vh4[row * 16 + l16];
    float p = sc[row];
    acc.x += p * vv.x; acc.y += p * vv.y; acc.z += p * vv.z; acc.w += p * vv.w;
  }
  // sum across the 4 row-groups within the wave
#pragma unroll
  for (int msk = 16; msk <= 32; msk <<= 1) {
    acc.x += __shfl_xor(acc.x, msk);
    acc.y += __shfl_xor(acc.y, msk);
    acc.z += __shfl_xor(acc.z, msk);
    acc.w += __shfl_xor(acc.w, msk);
  }
  if (grp == 0) ovec[w][l16] = acc;
  __syncthreads();

  if (w == 0 && grp == 0) {
    float4 o0 = ovec[0][l16], o1 = ovec[1][l16], o2 = ovec[2][l16], o3 = ovec[3][l16];
    float4 o = make_float4(o0.x + o1.x + o2.x + o3.x, o0.y + o1.y + o2.y + o3.y,
                           o0.z + o1.z + o2.z + o3.z, o0.w + o1.w + o2.w + o3.w);
    float* p = part + (size_t)(h * NCHUNK + c) * PREC;
    if (tid == 0) { p[0] = M; p[1] = S; }
    reinterpret_cast<float4*>(p + 4)[l16] = o;
  }
}

// ---------------------------------------------------------------------------
// Combine partials per head: 20 blocks x 64 threads.
// ---------------------------------------------------------------------------
__global__ __launch_bounds__(64) void attn_combine(
    const float* __restrict__ part, float* __restrict__ attn_out) {
  int h = blockIdx.x;
  int lane = threadIdx.x;
  const float* p = part + (size_t)h * NCHUNK * PREC;
  float M = -INFINITY;
#pragma unroll
  for (int c = 0; c < NCHUNK; ++c) M = fmaxf(M, p[c * PREC]);
  float S = 0.f, o = 0.f;
#pragma unroll
  for (int c = 0; c < NCHUNK; ++c) {
    float f = expf(p[c * PREC] - M);
    S += p[c * PREC + 1] * f;
    o += p[c * PREC + 4 + lane] * f;
  }
  attn_out[h * HDIM + lane] = o / S;
}

// ---------------------------------------------------------------------------

extern "C" void kernel_launch(void* const* d_in, const int* in_sizes, int n_in,
                              void* d_out, int out_size, void* d_ws, size_t ws_size,
                              hipStream_t stream) {
  const float* hs    = (const float*)d_in[0];  // [1280]
  const float* Kc    = (const float*)d_in[1];  // [20,8192,64]
  const float* Vc    = (const float*)d_in[2];  // [20,8192,64]
  const float* q_w   = (const float*)d_in[3];  // [1280,1280]
  const float* q_b   = (const float*)d_in[4];  // [1280]
  const float* out_w = (const float*)d_in[5];  // [1280,1280]
  const float* out_b = (const float*)d_in[6];  // [1280]
  float* out = (float*)d_out;                  // [1280]

  float* ws = (float*)d_ws;
  float* qv       = ws;                // 1280
  float* attn_out = ws + EMBED;        // 1280
  float* part     = ws + 2 * EMBED;    // 20*64*72 floats

  // 1. q projection (+ scale)
  matvec1280<<<EMBED / 4, 256, 0, stream>>>(q_w, hs, q_b, qv, QSCALE);
  // 2. flash-decode partials over (head, chunk)
  attn_partial<<<NHEAD * NCHUNK, 256, 0, stream>>>(Kc, Vc, qv, part);
  // 3. combine
  attn_combine<<<NHEAD, 64, 0, stream>>>(part, attn_out);
  // 4. output projection
  matvec1280<<<EMBED / 4, 256, 0, stream>>>(out_w, attn_out, out_b, out, 1.0f);
}